// Round 9
// baseline (165.762 us; speedup 1.0000x reference)
//
#include <hip/hip_runtime.h>
#include <hip/hip_bf16.h>

typedef __attribute__((ext_vector_type(4))) float f32x4;
typedef __attribute__((ext_vector_type(8))) short bf16x8;

// global -> LDS direct DMA, 16 B/lane. LDS dest = wave-uniform base + lane*16.
#define GLDS16(gp, lp) __builtin_amdgcn_global_load_lds( \
    (__attribute__((address_space(1))) void*)(void*)(gp), \
    (__attribute__((address_space(3))) void*)(lp), 16, 0, 0)

static constexpr int Mtot = 49152;   // 4*24*512 rows (b,h,n)
static constexpr int Otot = 512;
static constexpr int Hh   = 24;
// K order: k = i*6 + f (i: 0..119 = x-ch, 120..127 = t_emb; f: silu, rbf0..4)
// 8 K-iters of BK=96 = 12 chunks of 8 k.  Chunk-major LDS [chunk][row]x16B.
// R4 ENVELOPE, verbatim: 128x128 block, 4 waves 2x2, wave 64x64, acc[4][4],
// 48 KB LDS -> 3 blocks/CU (12 waves), stage-at-top GLDS covered by the gen
// VALU phase, one barrier pair per iter.  This is the measured optimum of 8
// structural variants (67.5 us); R7/R8 pipelining attempts both regressed.
// Micro change vs R4: gen restructured into two 4-channel SoA passes so the
// 5 quarter-rate transcendentals per channel issue as independent clusters
// (shorter dependency chains), transient pressure ~+10 VGPR (within budget).
// RBF constants e^{-4c^2} folded into Wt: basis = {silu, t*u^-2, t*u^-1, t,
// t*u, t*u^2}, t = exp(-4v^2), u = exp(4v)  (round-4..8-verified numerics).

__device__ inline unsigned short f2bf(float f) {
    __hip_bfloat16 h = __float2bfloat16(f);
    unsigned short u;
    __builtin_memcpy(&u, &h, 2);
    return u;
}

static constexpr float C1 = 0.36787944117f;   // e^-1
static constexpr float C4 = 0.01831563889f;   // e^-4

// Wt image: [cc(96)][col(512)] x 16B; 16B at (cc,col) = bf16 Ws[k=cc*8+e][col]
// with e^{-4c_g^2} folded: scale(f) = {1, C4, C1, 1, C1, C4}.
__global__ __launch_bounds__(256) void prep_W(
        const float* __restrict__ bw, const float* __restrict__ sw,
        uint4* __restrict__ Wt)
{
    const int tid = blockIdx.x * 256 + threadIdx.x;  // cc*512 + col; 49152 total
    const int col = tid & 511;
    const int cc  = tid >> 9;          // 0..95
    const int k0  = cc * 8;
    const float scale[6] = {1.0f, C4, C1, 1.0f, C1, C4};
    unsigned short s[8];
    #pragma unroll
    for (int e = 0; e < 8; ++e) {
        const int k = k0 + e;
        const int i = k / 6, f = k - i * 6;
        const float v = (f == 0) ? bw[col * 128 + i]
                                 : sw[(col * 128 + i) * 5 + (f - 1)] * scale[f];
        s[e] = f2bf(v);
    }
    uint4 u;
    u.x = s[0] | ((unsigned)s[1] << 16);
    u.y = s[2] | ((unsigned)s[3] << 16);
    u.z = s[4] | ((unsigned)s[5] << 16);
    u.w = s[6] | ((unsigned)s[7] << 16);
    Wt[tid] = u;
}

__global__ __launch_bounds__(256, 3) void gemm_kan(
        const float* __restrict__ x, const int* __restrict__ t_idx,
        const float* __restrict__ temb,
        const char* __restrict__ Wt,
        const float* __restrict__ bias,
        float* __restrict__ out)
{
    __shared__ char Alds[12 * 128 * 16];   // 24 KB, [chunk][row]x16B
    __shared__ char Blds[12 * 128 * 16];   // 24 KB, [chunk][col]x16B
    const int t    = threadIdx.x;
    const int wave = t >> 6;
    const int lane = t & 63;
    const int ll   = lane & 15;
    const int q4   = lane >> 4;
    const int wm   = (wave >> 1) * 64;
    const int wn   = (wave & 1) * 64;

    // bijective XCD swizzle: 1536 = 8*192, n fastest -> the 4 n-blocks of an
    // m-panel co-located on one XCD (x rows and Wt slice stay L2-hot).
    const int bid = blockIdx.x;
    const int swz = (bid & 7) * 192 + (bid >> 3);
    const int m_base = (swz >> 2) * 128;
    const int n_base = (swz & 3) * 128;

    // ---- A generation mapping: thread = (row, half of 16 channels) ----
    const int row = t >> 1;                     // 0..127
    const int hh  = t & 1;                      // channels hh*8 .. hh*8+7
    const int ht  = t_idx[(m_base >> 9) % Hh];  // uniform per block
    const float* xrow = x + (size_t)(m_base + row) * 120;
    const float* trow = temb + ht * 8;

    auto chanptr = [&](int i0) -> const float* {
        return (i0 < 120) ? (xrow + i0) : (trow + (i0 - 120));
    };

    f32x4 acc[4][4] = {};

    // prime x pipeline (iter 0: channels hh*8..hh*8+7; never straddles x/temb)
    float4 xa, xb;
    {
        const float* p = chanptr(hh * 8);
        xa = *(const float4*)p;
        xb = *(const float4*)(p + 4);
    }

    #pragma unroll
    for (int it = 0; it < 8; ++it) {
        // ---- stage B(it): wave stages chunks 3w..3w+2, 2 GLDS each (1 KB);
        //      in flight across the whole gen phase below ----
        #pragma unroll
        for (int j = 0; j < 6; ++j) {
            const int c = wave * 3 + (j >> 1);
            const int g = (j & 1) * 64;
            const char* src = Wt + (((size_t)(it * 12 + c) * 512 + n_base + g
                                     + lane) << 4);
            GLDS16(src, Blds + ((c * 128 + g) << 4));
        }

        const float4 ca = xa, cb = xb;
        if (it < 7) {                           // prefetch x for iter it+1
            const float* p = chanptr((it + 1) * 16 + hh * 8);
            xa = *(const float4*)p;
            xb = *(const float4*)(p + 4);
        }

        // ---- 8 channels x 6 features -> 48 bf16 (6 chunks), SoA in 2 groups
        const float v[8] = {ca.x, ca.y, ca.z, ca.w, cb.x, cb.y, cb.z, cb.w};
        unsigned short s[48];
        #pragma unroll
        for (int grp = 0; grp < 2; ++grp) {
            float se[4], tt[4], uu[4], rr[4];
            // cluster 1: independent transcendentals (quarter-rate) back-to-back
            #pragma unroll
            for (int c = 0; c < 4; ++c) {
                const float vv = v[grp * 4 + c];
                se[c] = __expf(-vv);
                tt[c] = __expf(-4.0f * vv * vv);
                uu[c] = __expf(4.0f * vv);
            }
            #pragma unroll
            for (int c = 0; c < 4; ++c) rr[c] = __builtin_amdgcn_rcpf(uu[c]);
            // cluster 2: dependent full-rate math + cvt
            #pragma unroll
            for (int c = 0; c < 4; ++c) {
                const int ci = grp * 4 + c;
                const float vv = v[ci];
                s[ci * 6 + 0] = f2bf(vv * __builtin_amdgcn_rcpf(1.0f + se[c]));
                const float tu = tt[c] * uu[c], tr = tt[c] * rr[c];
                s[ci * 6 + 1] = f2bf(tr * rr[c]);   // c_g = -1  (consts in Wt)
                s[ci * 6 + 2] = f2bf(tr);           // c_g = -0.5
                s[ci * 6 + 3] = f2bf(tt[c]);        // c_g = 0
                s[ci * 6 + 4] = f2bf(tu);           // c_g = +0.5
                s[ci * 6 + 5] = f2bf(tu * uu[c]);   // c_g = +1
            }
        }
        // ---- write 6 chunk-major 16B slots: ck = 6*hh + j ----
        #pragma unroll
        for (int j = 0; j < 6; ++j) {
            const int ck = 6 * hh + j;
            unsigned u[4];
            #pragma unroll
            for (int n = 0; n < 4; ++n)
                u[n] = s[j * 8 + 2 * n] | ((unsigned)s[j * 8 + 2 * n + 1] << 16);
            *(uint4*)(Alds + ((ck * 128 + row) << 4)) = make_uint4(u[0], u[1], u[2], u[3]);
        }
        __syncthreads();               // drain GLDS B (gen-covered) + ds_writes A

        #pragma unroll
        for (int kk = 0; kk < 3; ++kk) {
            const int ch = kk * 4 + q4;                  // chunk 0..11
            bf16x8 af[4], bf[4];
            #pragma unroll
            for (int mi = 0; mi < 4; ++mi)
                af[mi] = *(const bf16x8*)(Alds + ((ch * 128 + wm + mi * 16 + ll) << 4));
            #pragma unroll
            for (int ni = 0; ni < 4; ++ni)
                bf[ni] = *(const bf16x8*)(Blds + ((ch * 128 + wn + ni * 16 + ll) << 4));
            #pragma unroll
            for (int mi = 0; mi < 4; ++mi)
                #pragma unroll
                for (int ni = 0; ni < 4; ++ni)
                    acc[mi][ni] = __builtin_amdgcn_mfma_f32_16x16x32_bf16(
                        af[mi], bf[ni], acc[mi][ni], 0, 0, 0);
        }
        __syncthreads();               // LDS consumed before next stage
    }

    // C/D layout: col = lane&15, row = (lane>>4)*4 + reg  [m89-verified]
    const int col0 = n_base + wn + ll;
    const int row0 = m_base + wm + q4 * 4;
    #pragma unroll
    for (int ni = 0; ni < 4; ++ni) {
        const int col = col0 + ni * 16;
        const float bv = bias[col];
        #pragma unroll
        for (int mi = 0; mi < 4; ++mi) {
            #pragma unroll
            for (int r = 0; r < 4; ++r) {
                out[(long)(row0 + mi * 16 + r) * Otot + col] = acc[mi][ni][r] + bv;
            }
        }
    }
}

extern "C" void kernel_launch(void* const* d_in, const int* in_sizes, int n_in,
                              void* d_out, int out_size, void* d_ws, size_t ws_size,
                              hipStream_t stream) {
    const float* x    = (const float*)d_in[0];
    const int*   tidx = (const int*)  d_in[1];
    const float* temb = (const float*)d_in[2];
    const float* bw   = (const float*)d_in[3];
    const float* bb   = (const float*)d_in[4];
    const float* sw   = (const float*)d_in[5];
    float* out = (float*)d_out;

    char* Wt = (char*)d_ws;   // 96*512*16 = 768 KiB linear chunk-major image

    prep_W<<<49152 / 256, 256, 0, stream>>>(bw, sw, (uint4*)Wt);
    gemm_kan<<<1536, 256, 0, stream>>>(x, tidx, temb, Wt, bb, out);
}